// Round 1
// baseline (38.759 us; speedup 1.0000x reference)
//
#include <hip/hip_runtime.h>
#include <math.h>

#define BB 16
#define PP 2048
#define EPSF 1e-8f
#define SCALE (1.0f / (BB * PP))

// ---------------- Kernel A: transform points, init rowmin + out ----------------
__global__ __launch_bounds__(256) void init_transform_kernel(
    const float* __restrict__ R_t, const float* __restrict__ t_t,
    const float* __restrict__ R_p, const float* __restrict__ t_p,
    const float* __restrict__ mp,
    float4* __restrict__ pts_t, float4* __restrict__ pts_p,
    unsigned int* __restrict__ rowmin, float* __restrict__ out) {
  int idx = blockIdx.x * 256 + threadIdx.x;
  if (idx == 0) *out = 0.0f;
  if (idx < 2 * BB * PP) rowmin[idx] = 0x7f800000u;  // +inf bits
  if (idx < BB * PP) {
    int b = idx >> 11;  // / PP
    float x = mp[idx * 3 + 0], y = mp[idx * 3 + 1], z = mp[idx * 3 + 2];
    const float* R = R_t + b * 9;
    const float* t = t_t + b * 3;
    float4 o;
    o.x = fmaf(R[0], x, fmaf(R[1], y, fmaf(R[2], z, t[0])));
    o.y = fmaf(R[3], x, fmaf(R[4], y, fmaf(R[5], z, t[1])));
    o.z = fmaf(R[6], x, fmaf(R[7], y, fmaf(R[8], z, t[2])));
    o.w = 0.f;
    pts_t[idx] = o;
    R = R_p + b * 9;
    t = t_p + b * 3;
    o.x = fmaf(R[0], x, fmaf(R[1], y, fmaf(R[2], z, t[0])));
    o.y = fmaf(R[3], x, fmaf(R[4], y, fmaf(R[5], z, t[1])));
    o.z = fmaf(R[6], x, fmaf(R[7], y, fmaf(R[8], z, t[2])));
    o.w = 0.f;
    pts_p[idx] = o;
  }
}

// ---------------- Kernel B: pairwise min over tiles ----------------
// grid = 512 blocks: blk bits = b(4) | dir(1) | rowchunk(2) | colchunk(2)
// block = 256 threads; each block: 512 rows x 512 cols; 2 rows per thread.
__global__ __launch_bounds__(256) void pair_kernel(
    const float4* __restrict__ pts_t, const float4* __restrict__ pts_p,
    unsigned int* __restrict__ rowmin) {
  __shared__ float4 lds[512];  // 8 KB
  int blk = blockIdx.x;
  int cc  = blk & 3;
  int rc  = (blk >> 2) & 3;
  int dir = (blk >> 4) & 1;
  int b   = blk >> 5;
  const float4* Arows = dir ? pts_p : pts_t;
  const float4* Bcols = dir ? pts_t : pts_p;
  int colbase = cc * 512;
  for (int j = threadIdx.x; j < 512; j += 256)
    lds[j] = Bcols[b * PP + colbase + j];
  __syncthreads();
  int r0 = rc * 512 + threadIdx.x;
  int r1 = r0 + 256;
  float4 a0 = Arows[b * PP + r0];
  float4 a1 = Arows[b * PP + r1];
  float m0 = 3.4e38f, m1 = 3.4e38f;
#pragma unroll 4
  for (int j = 0; j < 512; ++j) {
    float4 q = lds[j];
    float dx = a0.x - q.x, dy = a0.y - q.y, dz = a0.z - q.z;
    float d = fmaf(dx, dx, fmaf(dy, dy, dz * dz));
    m0 = fminf(m0, d);
    dx = a1.x - q.x; dy = a1.y - q.y; dz = a1.z - q.z;
    d = fmaf(dx, dx, fmaf(dy, dy, dz * dz));
    m1 = fminf(m1, d);
  }
  unsigned int* rm = rowmin + (dir * BB + b) * PP;
  atomicMin(&rm[r0], __float_as_uint(m0));  // d2 >= 0 -> uint order == float order
  atomicMin(&rm[r1], __float_as_uint(m1));
}

// ---------------- Kernel C: sqrt + mean reduce ----------------
__global__ __launch_bounds__(256) void finish_kernel(
    const unsigned int* __restrict__ rowmin, float* __restrict__ out) {
  int idx = blockIdx.x * 256 + threadIdx.x;
  float v = sqrtf(__uint_as_float(rowmin[idx]) + EPSF) * SCALE;
  for (int off = 32; off; off >>= 1) v += __shfl_down(v, off, 64);
  __shared__ float wsum[4];
  if ((threadIdx.x & 63) == 0) wsum[threadIdx.x >> 6] = v;
  __syncthreads();
  if (threadIdx.x == 0) atomicAdd(out, wsum[0] + wsum[1] + wsum[2] + wsum[3]);
}

// ---------------- Fallback (tiny ws): self-contained, no scratch ----------------
// grid = 256: blk bits = b(4) | dir(1) | rowchunk(3); block = 256 threads, 1 row each.
__global__ __launch_bounds__(256) void fallback_kernel(
    const float* __restrict__ R_t, const float* __restrict__ t_t,
    const float* __restrict__ R_p, const float* __restrict__ t_p,
    const float* __restrict__ mp, float* __restrict__ out) {
  __shared__ float4 lds[PP];  // 32 KB
  int blk = blockIdx.x;
  int rc  = blk & 7;
  int dir = (blk >> 3) & 1;
  int b   = blk >> 4;
  const float* Rr = (dir ? R_p : R_t) + b * 9;
  const float* tr_ = (dir ? t_p : t_t) + b * 3;
  const float* Rc = (dir ? R_t : R_p) + b * 9;
  const float* tcp = (dir ? t_t : t_p) + b * 3;
  float c0 = Rc[0], c1 = Rc[1], c2 = Rc[2], c3 = Rc[3], c4 = Rc[4],
        c5 = Rc[5], c6 = Rc[6], c7 = Rc[7], c8 = Rc[8];
  float tc0 = tcp[0], tc1 = tcp[1], tc2 = tcp[2];
  for (int j = threadIdx.x; j < PP; j += 256) {
    int gi = (b * PP + j) * 3;
    float x = mp[gi], y = mp[gi + 1], z = mp[gi + 2];
    float4 q;
    q.x = fmaf(c0, x, fmaf(c1, y, fmaf(c2, z, tc0)));
    q.y = fmaf(c3, x, fmaf(c4, y, fmaf(c5, z, tc1)));
    q.z = fmaf(c6, x, fmaf(c7, y, fmaf(c8, z, tc2)));
    q.w = 0.f;
    lds[j] = q;
  }
  __syncthreads();
  int row = rc * 256 + threadIdx.x;
  int gi = (b * PP + row) * 3;
  float x = mp[gi], y = mp[gi + 1], z = mp[gi + 2];
  float ax = fmaf(Rr[0], x, fmaf(Rr[1], y, fmaf(Rr[2], z, tr_[0])));
  float ay = fmaf(Rr[3], x, fmaf(Rr[4], y, fmaf(Rr[5], z, tr_[1])));
  float az = fmaf(Rr[6], x, fmaf(Rr[7], y, fmaf(Rr[8], z, tr_[2])));
  float m = 3.4e38f;
#pragma unroll 8
  for (int j = 0; j < PP; ++j) {
    float4 q = lds[j];
    float dx = ax - q.x, dy = ay - q.y, dz = az - q.z;
    float d = fmaf(dx, dx, fmaf(dy, dy, dz * dz));
    m = fminf(m, d);
  }
  float v = sqrtf(m + EPSF) * SCALE;
  for (int off = 32; off; off >>= 1) v += __shfl_down(v, off, 64);
  __shared__ float wsum[4];
  if ((threadIdx.x & 63) == 0) wsum[threadIdx.x >> 6] = v;
  __syncthreads();
  if (threadIdx.x == 0) atomicAdd(out, wsum[0] + wsum[1] + wsum[2] + wsum[3]);
}

extern "C" void kernel_launch(void* const* d_in, const int* in_sizes, int n_in,
                              void* d_out, int out_size, void* d_ws, size_t ws_size,
                              hipStream_t stream) {
  const float* R_t = (const float*)d_in[0];
  const float* t_t = (const float*)d_in[1];
  const float* R_p = (const float*)d_in[2];
  const float* t_p = (const float*)d_in[3];
  const float* mp  = (const float*)d_in[4];
  float* out = (float*)d_out;

  size_t need = (size_t)BB * PP * sizeof(float4) * 2 +
                (size_t)2 * BB * PP * sizeof(unsigned int);
  if (ws_size >= need) {
    float4* pts_t = (float4*)d_ws;
    float4* pts_p = pts_t + BB * PP;
    unsigned int* rowmin = (unsigned int*)(pts_p + BB * PP);
    init_transform_kernel<<<256, 256, 0, stream>>>(R_t, t_t, R_p, t_p, mp,
                                                   pts_t, pts_p, rowmin, out);
    pair_kernel<<<512, 256, 0, stream>>>(pts_t, pts_p, rowmin);
    finish_kernel<<<256, 256, 0, stream>>>(rowmin, out);
  } else {
    hipMemsetAsync(d_out, 0, sizeof(float), stream);
    fallback_kernel<<<256, 256, 0, stream>>>(R_t, t_t, R_p, t_p, mp, out);
  }
}

// Round 2
// 27.268 us; speedup vs baseline: 1.4214x; 1.4214x over previous
//
#include <hip/hip_runtime.h>
#include <math.h>

#define BB 16
#define PP 2048
#define EPSF 1e-8f
#define SCALE (1.0f / (BB * PP))

// ---------------- Kernel A: transform points (2 forms), init rowmin + out ----
// Row form:  (x, y, z, |p|^2)
// Col form:  (-2x, -2y, -2z, |p|^2)
__global__ __launch_bounds__(256) void init_transform_kernel(
    const float* __restrict__ R_t, const float* __restrict__ t_t,
    const float* __restrict__ R_p, const float* __restrict__ t_p,
    const float* __restrict__ mp,
    float4* __restrict__ rowA_t, float4* __restrict__ colB_t,
    float4* __restrict__ rowA_p, float4* __restrict__ colB_p,
    unsigned int* __restrict__ rowmin, float* __restrict__ out) {
  int idx = blockIdx.x * 256 + threadIdx.x;
  if (idx == 0) *out = 0.0f;
  if (idx < 2 * BB * PP) rowmin[idx] = 0x7f7fffffu;  // FLT_MAX bits
  if (idx < BB * PP) {
    int b = idx >> 11;  // / PP
    float x = mp[idx * 3 + 0], y = mp[idx * 3 + 1], z = mp[idx * 3 + 2];
    {
      const float* R = R_t + b * 9;
      const float* t = t_t + b * 3;
      float px = fmaf(R[0], x, fmaf(R[1], y, fmaf(R[2], z, t[0])));
      float py = fmaf(R[3], x, fmaf(R[4], y, fmaf(R[5], z, t[1])));
      float pz = fmaf(R[6], x, fmaf(R[7], y, fmaf(R[8], z, t[2])));
      float w = fmaf(px, px, fmaf(py, py, pz * pz));
      rowA_t[idx] = make_float4(px, py, pz, w);
      colB_t[idx] = make_float4(-2.f * px, -2.f * py, -2.f * pz, w);
    }
    {
      const float* R = R_p + b * 9;
      const float* t = t_p + b * 3;
      float px = fmaf(R[0], x, fmaf(R[1], y, fmaf(R[2], z, t[0])));
      float py = fmaf(R[3], x, fmaf(R[4], y, fmaf(R[5], z, t[1])));
      float pz = fmaf(R[6], x, fmaf(R[7], y, fmaf(R[8], z, t[2])));
      float w = fmaf(px, px, fmaf(py, py, pz * pz));
      rowA_p[idx] = make_float4(px, py, pz, w);
      colB_p[idx] = make_float4(-2.f * px, -2.f * py, -2.f * pz, w);
    }
  }
}

// ---------------- Kernel B: pairwise min over tiles ----------------
// grid = 1024: blk bits = b(4) | dir(1) | rowchunk(2) | colchunk(3)
// block = 256 threads; each block: 512 rows x 256 cols; 2 rows/thread.
// Inner pair: s = q.w - 2 a.q  (3 fma), m = min(m, s). Row adds |a|^2 at end.
__global__ __launch_bounds__(256, 4) void pair_kernel(
    const float4* __restrict__ rowA_t, const float4* __restrict__ colB_t,
    const float4* __restrict__ rowA_p, const float4* __restrict__ colB_p,
    unsigned int* __restrict__ rowmin) {
  __shared__ float4 lds[256];  // 4 KB
  int blk = blockIdx.x;
  int cc  = blk & 7;
  int rc  = (blk >> 3) & 3;
  int dir = (blk >> 5) & 1;
  int b   = blk >> 6;
  const float4* Arows = dir ? rowA_p : rowA_t;
  const float4* Bcols = dir ? colB_t : colB_p;
  lds[threadIdx.x] = Bcols[b * PP + cc * 256 + threadIdx.x];
  __syncthreads();
  int r0 = rc * 512 + threadIdx.x;
  int r1 = r0 + 256;
  float4 a0 = Arows[b * PP + r0];
  float4 a1 = Arows[b * PP + r1];
  float m0a = 3.0e38f, m0b = 3.0e38f, m1a = 3.0e38f, m1b = 3.0e38f;
#pragma unroll 8
  for (int j = 0; j < 256; ++j) {
    float4 q = lds[j];
    float s0 = fmaf(a0.x, q.x, fmaf(a0.y, q.y, fmaf(a0.z, q.z, q.w)));
    float s1 = fmaf(a1.x, q.x, fmaf(a1.y, q.y, fmaf(a1.z, q.z, q.w)));
    if (j & 1) {
      m0b = fminf(m0b, s0);
      m1b = fminf(m1b, s1);
    } else {
      m0a = fminf(m0a, s0);
      m1a = fminf(m1a, s1);
    }
  }
  float d0 = fmaxf(a0.w + fminf(m0a, m0b), 0.0f);
  float d1 = fmaxf(a1.w + fminf(m1a, m1b), 0.0f);
  unsigned int* rm = rowmin + (dir * BB + b) * PP;
  atomicMin(&rm[r0], __float_as_uint(d0));  // nonneg -> uint order == float order
  atomicMin(&rm[r1], __float_as_uint(d1));
}

// ---------------- Kernel C: sqrt + mean reduce ----------------
__global__ __launch_bounds__(256) void finish_kernel(
    const unsigned int* __restrict__ rowmin, float* __restrict__ out) {
  int idx = blockIdx.x * 256 + threadIdx.x;
  float v = sqrtf(__uint_as_float(rowmin[idx]) + EPSF) * SCALE;
  for (int off = 32; off; off >>= 1) v += __shfl_down(v, off, 64);
  __shared__ float wsum[4];
  if ((threadIdx.x & 63) == 0) wsum[threadIdx.x >> 6] = v;
  __syncthreads();
  if (threadIdx.x == 0) atomicAdd(out, wsum[0] + wsum[1] + wsum[2] + wsum[3]);
}

// ---------------- Fallback (tiny ws): self-contained, no scratch ----------------
__global__ __launch_bounds__(256) void fallback_kernel(
    const float* __restrict__ R_t, const float* __restrict__ t_t,
    const float* __restrict__ R_p, const float* __restrict__ t_p,
    const float* __restrict__ mp, float* __restrict__ out) {
  __shared__ float4 lds[PP];  // 32 KB
  int blk = blockIdx.x;
  int rc  = blk & 7;
  int dir = (blk >> 3) & 1;
  int b   = blk >> 4;
  const float* Rr = (dir ? R_p : R_t) + b * 9;
  const float* tr_ = (dir ? t_p : t_t) + b * 3;
  const float* Rc = (dir ? R_t : R_p) + b * 9;
  const float* tcp = (dir ? t_t : t_p) + b * 3;
  float c0 = Rc[0], c1 = Rc[1], c2 = Rc[2], c3 = Rc[3], c4 = Rc[4],
        c5 = Rc[5], c6 = Rc[6], c7 = Rc[7], c8 = Rc[8];
  float tc0 = tcp[0], tc1 = tcp[1], tc2 = tcp[2];
  for (int j = threadIdx.x; j < PP; j += 256) {
    int gi = (b * PP + j) * 3;
    float x = mp[gi], y = mp[gi + 1], z = mp[gi + 2];
    float4 q;
    q.x = fmaf(c0, x, fmaf(c1, y, fmaf(c2, z, tc0)));
    q.y = fmaf(c3, x, fmaf(c4, y, fmaf(c5, z, tc1)));
    q.z = fmaf(c6, x, fmaf(c7, y, fmaf(c8, z, tc2)));
    q.w = 0.f;
    lds[j] = q;
  }
  __syncthreads();
  int row = rc * 256 + threadIdx.x;
  int gi = (b * PP + row) * 3;
  float x = mp[gi], y = mp[gi + 1], z = mp[gi + 2];
  float ax = fmaf(Rr[0], x, fmaf(Rr[1], y, fmaf(Rr[2], z, tr_[0])));
  float ay = fmaf(Rr[3], x, fmaf(Rr[4], y, fmaf(Rr[5], z, tr_[1])));
  float az = fmaf(Rr[6], x, fmaf(Rr[7], y, fmaf(Rr[8], z, tr_[2])));
  float m = 3.4e38f;
#pragma unroll 8
  for (int j = 0; j < PP; ++j) {
    float4 q = lds[j];
    float dx = ax - q.x, dy = ay - q.y, dz = az - q.z;
    float d = fmaf(dx, dx, fmaf(dy, dy, dz * dz));
    m = fminf(m, d);
  }
  float v = sqrtf(m + EPSF) * SCALE;
  for (int off = 32; off; off >>= 1) v += __shfl_down(v, off, 64);
  __shared__ float wsum[4];
  if ((threadIdx.x & 63) == 0) wsum[threadIdx.x >> 6] = v;
  __syncthreads();
  if (threadIdx.x == 0) atomicAdd(out, wsum[0] + wsum[1] + wsum[2] + wsum[3]);
}

extern "C" void kernel_launch(void* const* d_in, const int* in_sizes, int n_in,
                              void* d_out, int out_size, void* d_ws, size_t ws_size,
                              hipStream_t stream) {
  const float* R_t = (const float*)d_in[0];
  const float* t_t = (const float*)d_in[1];
  const float* R_p = (const float*)d_in[2];
  const float* t_p = (const float*)d_in[3];
  const float* mp  = (const float*)d_in[4];
  float* out = (float*)d_out;

  size_t need = (size_t)BB * PP * sizeof(float4) * 4 +
                (size_t)2 * BB * PP * sizeof(unsigned int);
  if (ws_size >= need) {
    float4* rowA_t = (float4*)d_ws;
    float4* colB_t = rowA_t + BB * PP;
    float4* rowA_p = colB_t + BB * PP;
    float4* colB_p = rowA_p + BB * PP;
    unsigned int* rowmin = (unsigned int*)(colB_p + BB * PP);
    init_transform_kernel<<<256, 256, 0, stream>>>(R_t, t_t, R_p, t_p, mp,
                                                   rowA_t, colB_t, rowA_p, colB_p,
                                                   rowmin, out);
    pair_kernel<<<1024, 256, 0, stream>>>(rowA_t, colB_t, rowA_p, colB_p, rowmin);
    finish_kernel<<<256, 256, 0, stream>>>(rowmin, out);
  } else {
    hipMemsetAsync(d_out, 0, sizeof(float), stream);
    fallback_kernel<<<256, 256, 0, stream>>>(R_t, t_t, R_p, t_p, mp, out);
  }
}

// Round 6
// 26.932 us; speedup vs baseline: 1.4391x; 1.0125x over previous
//
#include <hip/hip_runtime.h>
#include <math.h>

#define BB 16
#define PP 2048
#define EPSF 1e-8f
#define SCALE (1.0f / (BB * PP))
#define NCHUNK 8
#define CHUNK 256  // cols per block
#define RPT 8      // rows per thread

// ---------------- Kernel P: fused transform + pairwise partial min ----------
// grid = 256 blocks: blk = db(5 bits: b*2+dir) << 3 | colchunk(3)
// block = 256 threads; each block: ALL 2048 rows x 256 cols (8 rows/thread).
// partial layout: partial[cc][db][row]  (8 x 32 x 2048 floats = 2 MB)
__global__ __launch_bounds__(256) void pairtrans_kernel(
    const float* __restrict__ R_t, const float* __restrict__ t_t,
    const float* __restrict__ R_p, const float* __restrict__ t_p,
    const float* __restrict__ mp,
    float* __restrict__ partial, float* __restrict__ out) {
  __shared__ float4 tile[CHUNK];  // 4 KB
  int blk = blockIdx.x;
  int t = threadIdx.x;
  if (blk == 0 && t == 0) *out = 0.0f;  // finish runs after -> safe
  int cc = blk & 7;
  int db = blk >> 3;  // 0..31
  int dir = db & 1;
  int b = db >> 1;
  const float* Rr = (dir ? R_p : R_t) + b * 9;
  const float* tr_ = (dir ? t_p : t_t) + b * 3;
  const float* Rc = (dir ? R_t : R_p) + b * 9;
  const float* tc_ = (dir ? t_t : t_p) + b * 3;

  // --- transform this block's column point -> LDS (col form: -2q, |q|^2) ---
  {
    int ci = (b << 11) + (cc << 8) + t;
    float x = mp[ci * 3], y = mp[ci * 3 + 1], z = mp[ci * 3 + 2];
    float qx = fmaf(Rc[0], x, fmaf(Rc[1], y, fmaf(Rc[2], z, tc_[0])));
    float qy = fmaf(Rc[3], x, fmaf(Rc[4], y, fmaf(Rc[5], z, tc_[1])));
    float qz = fmaf(Rc[6], x, fmaf(Rc[7], y, fmaf(Rc[8], z, tc_[2])));
    float qw = fmaf(qx, qx, fmaf(qy, qy, qz * qz));
    tile[t] = make_float4(-2.f * qx, -2.f * qy, -2.f * qz, qw);
  }

  // --- transform this thread's 8 rows -> registers (row form: p, |p|^2) ---
  float r0 = Rr[0], r1 = Rr[1], r2 = Rr[2], r3 = Rr[3], r4 = Rr[4],
        r5 = Rr[5], r6 = Rr[6], r7 = Rr[7], r8 = Rr[8];
  float t0 = tr_[0], t1 = tr_[1], t2 = tr_[2];
  float4 a[RPT];
#pragma unroll
  for (int k = 0; k < RPT; ++k) {
    int ri = (b << 11) + (k << 8) + t;
    float x = mp[ri * 3], y = mp[ri * 3 + 1], z = mp[ri * 3 + 2];
    float px = fmaf(r0, x, fmaf(r1, y, fmaf(r2, z, t0)));
    float py = fmaf(r3, x, fmaf(r4, y, fmaf(r5, z, t1)));
    float pz = fmaf(r6, x, fmaf(r7, y, fmaf(r8, z, t2)));
    a[k] = make_float4(px, py, pz, fmaf(px, px, fmaf(py, py, pz * pz)));
  }
  __syncthreads();

  float m[RPT];
#pragma unroll
  for (int k = 0; k < RPT; ++k) m[k] = 3.0e38f;

#pragma unroll 4
  for (int j = 0; j < CHUNK; j += 2) {
    float4 q0 = tile[j];
    float4 q1 = tile[j + 1];
#pragma unroll
    for (int k = 0; k < RPT; ++k) {
      float s0 = fmaf(a[k].x, q0.x, fmaf(a[k].y, q0.y, fmaf(a[k].z, q0.z, q0.w)));
      float s1 = fmaf(a[k].x, q1.x, fmaf(a[k].y, q1.y, fmaf(a[k].z, q1.z, q1.w)));
      m[k] = fminf(fminf(m[k], s0), s1);  // -> v_min3_f32
    }
  }

  float* pp = partial + (cc << 16) + (db << 11) + t;
#pragma unroll
  for (int k = 0; k < RPT; ++k) pp[k << 8] = m[k] + a[k].w;
}

// ---------------- Kernel F: reduce chunks + sqrt + mean ----------------
__global__ __launch_bounds__(256) void finish_kernel(
    const float* __restrict__ partial, float* __restrict__ out) {
  int idx = blockIdx.x * 256 + threadIdx.x;  // 0..65535 = db*2048+row
  float v = partial[idx];
#pragma unroll
  for (int c = 1; c < NCHUNK; ++c) v = fminf(v, partial[(c << 16) + idx]);
  v = fmaxf(v, 0.0f);  // guard tiny negative from cancellation
  float s = sqrtf(v + EPSF) * SCALE;
  for (int off = 32; off; off >>= 1) s += __shfl_down(s, off, 64);
  __shared__ float wsum[4];
  if ((threadIdx.x & 63) == 0) wsum[threadIdx.x >> 6] = s;
  __syncthreads();
  if (threadIdx.x == 0) atomicAdd(out, wsum[0] + wsum[1] + wsum[2] + wsum[3]);
}

// ---------------- Fallback (tiny ws): self-contained, no scratch ------------
__global__ __launch_bounds__(256) void fallback_kernel(
    const float* __restrict__ R_t, const float* __restrict__ t_t,
    const float* __restrict__ R_p, const float* __restrict__ t_p,
    const float* __restrict__ mp, float* __restrict__ out) {
  __shared__ float4 lds[PP];  // 32 KB
  int blk = blockIdx.x;
  int rc  = blk & 7;
  int dir = (blk >> 3) & 1;
  int b   = blk >> 4;
  const float* Rr = (dir ? R_p : R_t) + b * 9;
  const float* tr_ = (dir ? t_p : t_t) + b * 3;
  const float* Rc = (dir ? R_t : R_p) + b * 9;
  const float* tcp = (dir ? t_t : t_p) + b * 3;
  float c0 = Rc[0], c1 = Rc[1], c2 = Rc[2], c3 = Rc[3], c4 = Rc[4],
        c5 = Rc[5], c6 = Rc[6], c7 = Rc[7], c8 = Rc[8];
  float tc0 = tcp[0], tc1 = tcp[1], tc2 = tcp[2];
  for (int j = threadIdx.x; j < PP; j += 256) {
    int gi = (b * PP + j) * 3;
    float x = mp[gi], y = mp[gi + 1], z = mp[gi + 2];
    float4 q;
    q.x = fmaf(c0, x, fmaf(c1, y, fmaf(c2, z, tc0)));
    q.y = fmaf(c3, x, fmaf(c4, y, fmaf(c5, z, tc1)));
    q.z = fmaf(c6, x, fmaf(c7, y, fmaf(c8, z, tc2)));
    q.w = 0.f;
    lds[j] = q;
  }
  __syncthreads();
  int row = rc * 256 + threadIdx.x;
  int gi = (b * PP + row) * 3;
  float x = mp[gi], y = mp[gi + 1], z = mp[gi + 2];
  float ax = fmaf(Rr[0], x, fmaf(Rr[1], y, fmaf(Rr[2], z, tr_[0])));
  float ay = fmaf(Rr[3], x, fmaf(Rr[4], y, fmaf(Rr[5], z, tr_[1])));
  float az = fmaf(Rr[6], x, fmaf(Rr[7], y, fmaf(Rr[8], z, tr_[2])));
  float m = 3.4e38f;
#pragma unroll 8
  for (int j = 0; j < PP; ++j) {
    float4 q = lds[j];
    float dx = ax - q.x, dy = ay - q.y, dz = az - q.z;
    float d = fmaf(dx, dx, fmaf(dy, dy, dz * dz));
    m = fminf(m, d);
  }
  float v = sqrtf(m + EPSF) * SCALE;
  for (int off = 32; off; off >>= 1) v += __shfl_down(v, off, 64);
  __shared__ float wsum[4];
  if ((threadIdx.x & 63) == 0) wsum[threadIdx.x >> 6] = v;
  __syncthreads();
  if (threadIdx.x == 0) atomicAdd(out, wsum[0] + wsum[1] + wsum[2] + wsum[3]);
}

extern "C" void kernel_launch(void* const* d_in, const int* in_sizes, int n_in,
                              void* d_out, int out_size, void* d_ws, size_t ws_size,
                              hipStream_t stream) {
  const float* R_t = (const float*)d_in[0];
  const float* t_t = (const float*)d_in[1];
  const float* R_p = (const float*)d_in[2];
  const float* t_p = (const float*)d_in[3];
  const float* mp  = (const float*)d_in[4];
  float* out = (float*)d_out;

  size_t need = (size_t)NCHUNK * 2 * BB * PP * sizeof(float);  // 2 MB
  if (ws_size >= need) {
    float* partial = (float*)d_ws;
    pairtrans_kernel<<<256, 256, 0, stream>>>(R_t, t_t, R_p, t_p, mp, partial, out);
    finish_kernel<<<256, 256, 0, stream>>>(partial, out);
  } else {
    hipMemsetAsync(d_out, 0, sizeof(float), stream);
    fallback_kernel<<<256, 256, 0, stream>>>(R_t, t_t, R_p, t_p, mp, out);
  }
}

// Round 7
// 25.614 us; speedup vs baseline: 1.5132x; 1.0515x over previous
//
#include <hip/hip_runtime.h>
#include <math.h>

#define BB 16
#define PP 2048
#define EPSF 1e-8f
#define SCALE (1.0f / (BB * PP))
#define NCHUNK 32
#define CHUNK 64   // cols per block
#define RPT 8      // rows per thread

// ---------------- Kernel P: fused transform + pairwise partial min ----------
// grid = 1024 blocks: blk = db(5 bits: b*2+dir) << 5 | colchunk(5)
// block = 256 threads; each block: ALL 2048 rows x 64 cols (8 rows/thread).
// 4 blocks/CU -> 4 waves/SIMD for latency hiding; RPT=8 keeps VALU > LDS pipe.
// partial layout: partial[cc][db][row]  (32 x 32 x 2048 floats = 8 MB)
__global__ __launch_bounds__(256) void pairtrans_kernel(
    const float* __restrict__ R_t, const float* __restrict__ t_t,
    const float* __restrict__ R_p, const float* __restrict__ t_p,
    const float* __restrict__ mp,
    float* __restrict__ partial, float* __restrict__ out) {
  __shared__ float4 tile[CHUNK];  // 1 KB
  int blk = blockIdx.x;
  int t = threadIdx.x;
  if (blk == 0 && t == 0) *out = 0.0f;  // finish runs after -> safe
  int cc = blk & 31;
  int db = blk >> 5;  // 0..31
  int dir = db & 1;
  int b = db >> 1;
  const float* Rr = (dir ? R_p : R_t) + b * 9;
  const float* tr_ = (dir ? t_p : t_t) + b * 3;
  const float* Rc = (dir ? R_t : R_p) + b * 9;
  const float* tc_ = (dir ? t_t : t_p) + b * 3;

  // --- transform this block's column points -> LDS (col form: -2q, |q|^2) ---
  if (t < CHUNK) {
    int ci = (b << 11) + (cc << 6) + t;
    float x = mp[ci * 3], y = mp[ci * 3 + 1], z = mp[ci * 3 + 2];
    float qx = fmaf(Rc[0], x, fmaf(Rc[1], y, fmaf(Rc[2], z, tc_[0])));
    float qy = fmaf(Rc[3], x, fmaf(Rc[4], y, fmaf(Rc[5], z, tc_[1])));
    float qz = fmaf(Rc[6], x, fmaf(Rc[7], y, fmaf(Rc[8], z, tc_[2])));
    float qw = fmaf(qx, qx, fmaf(qy, qy, qz * qz));
    tile[t] = make_float4(-2.f * qx, -2.f * qy, -2.f * qz, qw);
  }

  // --- transform this thread's 8 rows -> registers (row form: p, |p|^2) ---
  float r0 = Rr[0], r1 = Rr[1], r2 = Rr[2], r3 = Rr[3], r4 = Rr[4],
        r5 = Rr[5], r6 = Rr[6], r7 = Rr[7], r8 = Rr[8];
  float t0 = tr_[0], t1 = tr_[1], t2 = tr_[2];
  float4 a[RPT];
#pragma unroll
  for (int k = 0; k < RPT; ++k) {
    int ri = (b << 11) + (k << 8) + t;
    float x = mp[ri * 3], y = mp[ri * 3 + 1], z = mp[ri * 3 + 2];
    float px = fmaf(r0, x, fmaf(r1, y, fmaf(r2, z, t0)));
    float py = fmaf(r3, x, fmaf(r4, y, fmaf(r5, z, t1)));
    float pz = fmaf(r6, x, fmaf(r7, y, fmaf(r8, z, t2)));
    a[k] = make_float4(px, py, pz, fmaf(px, px, fmaf(py, py, pz * pz)));
  }
  __syncthreads();

  float m[RPT];
#pragma unroll
  for (int k = 0; k < RPT; ++k) m[k] = 3.0e38f;

#pragma unroll 4
  for (int j = 0; j < CHUNK; j += 2) {
    float4 q0 = tile[j];
    float4 q1 = tile[j + 1];
#pragma unroll
    for (int k = 0; k < RPT; ++k) {
      float s0 = fmaf(a[k].x, q0.x, fmaf(a[k].y, q0.y, fmaf(a[k].z, q0.z, q0.w)));
      float s1 = fmaf(a[k].x, q1.x, fmaf(a[k].y, q1.y, fmaf(a[k].z, q1.z, q1.w)));
      m[k] = fminf(fminf(m[k], s0), s1);  // -> v_min3_f32
    }
  }

  float* pp = partial + (cc << 16) + (db << 11) + t;
#pragma unroll
  for (int k = 0; k < RPT; ++k) pp[k << 8] = m[k] + a[k].w;
}

// ---------------- Kernel F: reduce chunks + sqrt + mean ----------------
__global__ __launch_bounds__(256) void finish_kernel(
    const float* __restrict__ partial, float* __restrict__ out) {
  int idx = blockIdx.x * 256 + threadIdx.x;  // 0..65535 = db*2048+row
  float v = partial[idx];
#pragma unroll
  for (int c = 1; c < NCHUNK; ++c) v = fminf(v, partial[(c << 16) + idx]);
  v = fmaxf(v, 0.0f);  // guard tiny negative from cancellation
  float s = sqrtf(v + EPSF) * SCALE;
  for (int off = 32; off; off >>= 1) s += __shfl_down(s, off, 64);
  __shared__ float wsum[4];
  if ((threadIdx.x & 63) == 0) wsum[threadIdx.x >> 6] = s;
  __syncthreads();
  if (threadIdx.x == 0) atomicAdd(out, wsum[0] + wsum[1] + wsum[2] + wsum[3]);
}

// ---------------- Fallback (tiny ws): self-contained, no scratch ------------
__global__ __launch_bounds__(256) void fallback_kernel(
    const float* __restrict__ R_t, const float* __restrict__ t_t,
    const float* __restrict__ R_p, const float* __restrict__ t_p,
    const float* __restrict__ mp, float* __restrict__ out) {
  __shared__ float4 lds[PP];  // 32 KB
  int blk = blockIdx.x;
  int rc  = blk & 7;
  int dir = (blk >> 3) & 1;
  int b   = blk >> 4;
  const float* Rr = (dir ? R_p : R_t) + b * 9;
  const float* tr_ = (dir ? t_p : t_t) + b * 3;
  const float* Rc = (dir ? R_t : R_p) + b * 9;
  const float* tcp = (dir ? t_t : t_p) + b * 3;
  float c0 = Rc[0], c1 = Rc[1], c2 = Rc[2], c3 = Rc[3], c4 = Rc[4],
        c5 = Rc[5], c6 = Rc[6], c7 = Rc[7], c8 = Rc[8];
  float tc0 = tcp[0], tc1 = tcp[1], tc2 = tcp[2];
  for (int j = threadIdx.x; j < PP; j += 256) {
    int gi = (b * PP + j) * 3;
    float x = mp[gi], y = mp[gi + 1], z = mp[gi + 2];
    float4 q;
    q.x = fmaf(c0, x, fmaf(c1, y, fmaf(c2, z, tc0)));
    q.y = fmaf(c3, x, fmaf(c4, y, fmaf(c5, z, tc1)));
    q.z = fmaf(c6, x, fmaf(c7, y, fmaf(c8, z, tc2)));
    q.w = 0.f;
    lds[j] = q;
  }
  __syncthreads();
  int row = rc * 256 + threadIdx.x;
  int gi = (b * PP + row) * 3;
  float x = mp[gi], y = mp[gi + 1], z = mp[gi + 2];
  float ax = fmaf(Rr[0], x, fmaf(Rr[1], y, fmaf(Rr[2], z, tr_[0])));
  float ay = fmaf(Rr[3], x, fmaf(Rr[4], y, fmaf(Rr[5], z, tr_[1])));
  float az = fmaf(Rr[6], x, fmaf(Rr[7], y, fmaf(Rr[8], z, tr_[2])));
  float m = 3.4e38f;
#pragma unroll 8
  for (int j = 0; j < PP; ++j) {
    float4 q = lds[j];
    float dx = ax - q.x, dy = ay - q.y, dz = az - q.z;
    float d = fmaf(dx, dx, fmaf(dy, dy, dz * dz));
    m = fminf(m, d);
  }
  float v = sqrtf(m + EPSF) * SCALE;
  for (int off = 32; off; off >>= 1) v += __shfl_down(v, off, 64);
  __shared__ float wsum[4];
  if ((threadIdx.x & 63) == 0) wsum[threadIdx.x >> 6] = v;
  __syncthreads();
  if (threadIdx.x == 0) atomicAdd(out, wsum[0] + wsum[1] + wsum[2] + wsum[3]);
}

extern "C" void kernel_launch(void* const* d_in, const int* in_sizes, int n_in,
                              void* d_out, int out_size, void* d_ws, size_t ws_size,
                              hipStream_t stream) {
  const float* R_t = (const float*)d_in[0];
  const float* t_t = (const float*)d_in[1];
  const float* R_p = (const float*)d_in[2];
  const float* t_p = (const float*)d_in[3];
  const float* mp  = (const float*)d_in[4];
  float* out = (float*)d_out;

  size_t need = (size_t)NCHUNK * 2 * BB * PP * sizeof(float);  // 8 MB
  if (ws_size >= need) {
    float* partial = (float*)d_ws;
    pairtrans_kernel<<<1024, 256, 0, stream>>>(R_t, t_t, R_p, t_p, mp, partial, out);
    finish_kernel<<<256, 256, 0, stream>>>(partial, out);
  } else {
    hipMemsetAsync(d_out, 0, sizeof(float), stream);
    fallback_kernel<<<256, 256, 0, stream>>>(R_t, t_t, R_p, t_p, mp, out);
  }
}